// Round 2
// baseline (1254.880 us; speedup 1.0000x reference)
//
#include <hip/hip_runtime.h>
#include <hip/hip_bf16.h>
#include <math.h>

#define BB 8
#define CC 64
#define HH 128
#define WW 128
#define OO 64
#define HWHW (HH*WW)

typedef short bf16x8 __attribute__((ext_vector_type(8)));
typedef float f32x4 __attribute__((ext_vector_type(4)));

// ---------------- Kernel 1: NCHW -> NHWC transpose of x ----------------
__global__ __launch_bounds__(256) void k_transpose(const float* __restrict__ x,
                                                   float* __restrict__ xt) {
  __shared__ float tile[64][65];
  int blk = blockIdx.x;            // 2048 blocks: 8 batches * 256 hw-chunks
  int b = blk >> 8;
  int hw0 = (blk & 255) << 6;      // 64 hw positions per block
  int lane = threadIdx.x & 63;
  int g = threadIdx.x >> 6;        // 0..3
  const float* xb = x + (size_t)b * CC * HWHW;
#pragma unroll
  for (int i = 0; i < 16; ++i) {
    int c = g + i * 4;
    tile[lane][c] = xb[c * HWHW + hw0 + lane];   // coalesced read along hw
  }
  __syncthreads();
  float* xtb = xt + (size_t)b * HWHW * CC;
#pragma unroll
  for (int j = 0; j < 16; ++j) {
    int hwl = g + j * 4;
    xtb[(size_t)(hw0 + hwl) * 64 + lane] = tile[hwl][lane];  // coalesced along c
  }
}

// ---------------- Kernel 2: cast w_dcn [O][576] fp32 -> bf16 (same layout) ----------------
__global__ __launch_bounds__(256) void k_wcast(const float* __restrict__ w,
                                               unsigned short* __restrict__ wbf) {
  int i = blockIdx.x * 256 + threadIdx.x;  // 36864 elements
  __hip_bfloat16 h = __float2bfloat16(w[i]);
  wbf[i] = *(unsigned short*)&h;
}

// ---------------- Kernel 3: fused offset+mask 3x3 conv (fp32 VALU) ----------------
__global__ __launch_bounds__(256) void k_convom(const float* __restrict__ x,
                                                const float* __restrict__ w_off,
                                                const float* __restrict__ b_off,
                                                const float* __restrict__ w_mask,
                                                const float* __restrict__ b_mask,
                                                float* __restrict__ off_out,
                                                float* __restrict__ mask_out) {
  __shared__ float wlds[27 * 576];   // 62,208 B
  for (int i = threadIdx.x; i < 18 * 576; i += 256) wlds[i] = w_off[i];
  for (int i = threadIdx.x; i < 9 * 576; i += 256) wlds[18 * 576 + i] = w_mask[i];
  __syncthreads();

  int t = blockIdx.x * 256 + threadIdx.x;  // 65536 threads, 2 px each
  int pix = t * 2;
  int b = pix / HWHW;
  int hw = pix % HWHW;
  int y = hw / WW;
  int x0 = hw % WW;                        // even, pair stays in row

  float acc[27][2];
#pragma unroll
  for (int ch = 0; ch < 27; ++ch) { acc[ch][0] = 0.f; acc[ch][1] = 0.f; }

  const float* xb = x + (size_t)b * CC * HWHW;
  for (int c = 0; c < CC; ++c) {
    float xv[3][4];
#pragma unroll
    for (int r = 0; r < 3; ++r) {
      int yy = y + r - 1;
      bool yok = ((unsigned)yy < (unsigned)HH);
      const float* rowp = xb + c * HWHW + yy * WW;
#pragma unroll
      for (int q = 0; q < 4; ++q) {
        int xx = x0 + q - 1;
        bool ok = yok && ((unsigned)xx < (unsigned)WW);
        xv[r][q] = ok ? rowp[xx] : 0.f;
      }
    }
    const float* wc = &wlds[c * 9];
#pragma unroll
    for (int ch = 0; ch < 27; ++ch) {
      const float* wp = wc + ch * 576;
#pragma unroll
      for (int r = 0; r < 3; ++r) {
#pragma unroll
        for (int q = 0; q < 3; ++q) {
          float wv = wp[r * 3 + q];
          acc[ch][0] += xv[r][q] * wv;
          acc[ch][1] += xv[r][q + 1] * wv;
        }
      }
    }
  }

  int base_off = b * 18 * HWHW + y * WW + x0;
#pragma unroll
  for (int ch = 0; ch < 18; ++ch) {
    float bb = b_off[ch];
    off_out[base_off + ch * HWHW] = acc[ch][0] + bb;
    off_out[base_off + ch * HWHW + 1] = acc[ch][1] + bb;
  }
  int base_m = b * 9 * HWHW + y * WW + x0;
#pragma unroll
  for (int ch = 0; ch < 9; ++ch) {
    float bb = b_mask[ch];
    float v0 = acc[18 + ch][0] + bb;
    float v1 = acc[18 + ch][1] + bb;
    mask_out[base_m + ch * HWHW] = 1.f / (1.f + expf(-v0));
    mask_out[base_m + ch * HWHW + 1] = 1.f / (1.f + expf(-v1));
  }
}

// ---------------- Kernel 4: deformable conv — bf16 gather + MFMA ----------------
// Block = 256 thr (4 waves), 16 consecutive-x pixels (one row).
// Phase 1: wave gathers 4 px x 9 taps, lane=channel, branch-free bilinear,
//          writes bf16 to LDS cols[16][CSTR].
// Phase 2: wave w owns out-channels w*16..w*16+15; 18 K-steps of
//          mfma_f32_16x16x32_bf16 with A from LDS, B from global bf16 w.
#define CSTR 584   // padded row stride in bf16 elems (584*2 B = 73*16 B)
__global__ __launch_bounds__(256, 8) void k_deform(const float* __restrict__ xt,
                                                   const float* __restrict__ off,
                                                   const float* __restrict__ msk,
                                                   const unsigned short* __restrict__ wbf,
                                                   float* __restrict__ out) {
  __shared__ unsigned short cols[16 * CSTR];  // 18,688 B
  int blk = blockIdx.x;          // 8192 blocks
  int pix0 = blk * 16;
  int b = pix0 / HWHW;
  int hw0 = pix0 % HWHW;
  int y = hw0 / WW;
  int x0 = hw0 % WW;             // 16 consecutive x in one row
  int wave = threadIdx.x >> 6;
  int lane = threadIdx.x & 63;   // = input channel c in phase 1
  const float* xb = xt + (size_t)b * HWHW * 64;

#pragma unroll
  for (int pp = 0; pp < 4; ++pp) {
    int p = wave * 4 + pp;
    int xx = x0 + p;
    const float* offp = off + (size_t)b * 18 * HWHW + y * WW + xx;
    const float* mp = msk + (size_t)b * 9 * HWHW + y * WW + xx;
#pragma unroll
    for (int k = 0; k < 9; ++k) {
      float dy = offp[(2 * k) * HWHW];
      float dx = offp[(2 * k + 1) * HWHW];
      float m = mp[k * HWHW];
      float py = (float)(y + k / 3 - 1) + dy;
      float px = (float)(xx + k % 3 - 1) + dx;
      float fy = floorf(py);
      float fx = floorf(px);
      int y0i = (int)fy;
      int x0i = (int)fx;
      float wy1 = py - fy;
      float wx1 = px - fx;
      float wy0 = 1.f - wy1;
      float wx0 = 1.f - wx1;
      // validity as multiplicative flags (branch-free)
      float vy0 = ((unsigned)y0i < (unsigned)HH) ? 1.f : 0.f;
      float vy1 = ((unsigned)(y0i + 1) < (unsigned)HH) ? 1.f : 0.f;
      float vx0 = ((unsigned)x0i < (unsigned)WW) ? 1.f : 0.f;
      float vx1 = ((unsigned)(x0i + 1) < (unsigned)WW) ? 1.f : 0.f;
      int y0c = min(max(y0i, 0), HH - 1);
      int y1c = min(max(y0i + 1, 0), HH - 1);
      int x0c = min(max(x0i, 0), WW - 1);
      int x1c = min(max(x0i + 1, 0), WW - 1);
      const float* r0 = xb + (size_t)(y0c * WW) * 64 + lane;
      const float* r1 = xb + (size_t)(y1c * WW) * 64 + lane;
      float v00 = r0[x0c * 64];
      float v01 = r0[x1c * 64];
      float v10 = r1[x0c * 64];
      float v11 = r1[x1c * 64];
      float w00 = wy0 * wx0 * vy0 * vx0;
      float w01 = wy0 * wx1 * vy0 * vx1;
      float w10 = wy1 * wx0 * vy1 * vx0;
      float w11 = wy1 * wx1 * vy1 * vx1;
      float val = (v00 * w00 + v01 * w01 + v10 * w10 + v11 * w11) * m;
      __hip_bfloat16 h = __float2bfloat16(val);
      cols[p * CSTR + lane * 9 + k] = *(unsigned short*)&h;
    }
  }
  __syncthreads();

  // Phase 2: MFMA. A[m][k] = cols[m][k] (pixels x 576), B[k][n] = w[n][k].
  int mrow = lane & 15;        // A row (pixel) for A-frag; B col (o) for B-frag
  int kgrp = lane >> 4;        // k sub-group 0..3
  int otile = wave * 16;
  f32x4 acc = {0.f, 0.f, 0.f, 0.f};
  const unsigned short* wp = wbf + (size_t)(otile + mrow) * 576 + kgrp * 8;
  const unsigned short* cp = &cols[mrow * CSTR + kgrp * 8];
#pragma unroll
  for (int s = 0; s < 18; ++s) {
    bf16x8 a = *(const bf16x8*)(cp + s * 32);
    bf16x8 bb = *(const bf16x8*)(wp + s * 32);
    acc = __builtin_amdgcn_mfma_f32_16x16x32_bf16(a, bb, acc, 0, 0, 0);
  }
  // C/D layout: lane holds D[row=(lane>>4)*4+r][col=lane&15]; row=pixel, col=o.
  int o = otile + mrow;
  float* op = out + (size_t)(b * 64 + o) * HWHW + y * WW + x0 + kgrp * 4;
  *(f32x4*)op = acc;
}

extern "C" void kernel_launch(void* const* d_in, const int* in_sizes, int n_in,
                              void* d_out, int out_size, void* d_ws, size_t ws_size,
                              hipStream_t stream) {
  const float* x = (const float*)d_in[0];
  const float* w_off = (const float*)d_in[1];
  const float* b_off = (const float*)d_in[2];
  const float* w_mask = (const float*)d_in[3];
  const float* b_mask = (const float*)d_in[4];
  const float* w_dcn = (const float*)d_in[5];
  float* out = (float*)d_out;

  char* ws = (char*)d_ws;
  float* xt = (float*)ws;                                  // 33,554,432 B
  float* off = (float*)(ws + 33554432);                    //  9,437,184 B
  float* msk = (float*)(ws + 33554432 + 9437184);          //  4,718,592 B
  unsigned short* wbf = (unsigned short*)(ws + 33554432 + 9437184 + 4718592); // 73,728 B

  hipLaunchKernelGGL(k_transpose, dim3(2048), dim3(256), 0, stream, x, xt);
  hipLaunchKernelGGL(k_wcast, dim3(144), dim3(256), 0, stream, w_dcn, wbf);
  hipLaunchKernelGGL(k_convom, dim3(256), dim3(256), 0, stream, x, w_off, b_off,
                     w_mask, b_mask, off, msk);
  hipLaunchKernelGGL(k_deform, dim3(8192), dim3(256), 0, stream, xt, off, msk, wbf, out);
}

// Round 3
// 488.840 us; speedup vs baseline: 2.5671x; 2.5671x over previous
//
#include <hip/hip_runtime.h>
#include <hip/hip_bf16.h>
#include <math.h>

#define BB 8
#define CC 64
#define HH 128
#define WW 128
#define OO 64
#define HWHW (HH*WW)

typedef short bf16x8 __attribute__((ext_vector_type(8)));
typedef float f32x4 __attribute__((ext_vector_type(4)));

// ---------------- Kernel 1: NCHW -> NHWC transpose of x ----------------
__global__ __launch_bounds__(256) void k_transpose(const float* __restrict__ x,
                                                   float* __restrict__ xt) {
  __shared__ float tile[64][65];
  int blk = blockIdx.x;            // 2048 blocks: 8 batches * 256 hw-chunks
  int b = blk >> 8;
  int hw0 = (blk & 255) << 6;      // 64 hw positions per block
  int lane = threadIdx.x & 63;
  int g = threadIdx.x >> 6;        // 0..3
  const float* xb = x + (size_t)b * CC * HWHW;
#pragma unroll
  for (int i = 0; i < 16; ++i) {
    int c = g + i * 4;
    tile[lane][c] = xb[c * HWHW + hw0 + lane];   // coalesced read along hw
  }
  __syncthreads();
  float* xtb = xt + (size_t)b * HWHW * CC;
#pragma unroll
  for (int j = 0; j < 16; ++j) {
    int hwl = g + j * 4;
    xtb[(size_t)(hw0 + hwl) * 64 + lane] = tile[hwl][lane];  // coalesced along c
  }
}

// ---------------- Kernel 2: cast w_dcn [O][576] fp32 -> bf16 (same layout) ----------------
__global__ __launch_bounds__(256) void k_wcast(const float* __restrict__ w,
                                               unsigned short* __restrict__ wbf) {
  int i = blockIdx.x * 256 + threadIdx.x;  // 36864 elements
  __hip_bfloat16 h = __float2bfloat16(w[i]);
  wbf[i] = *(unsigned short*)&h;
}

// ---------------- Kernel 3: fused offset+mask 3x3 conv (fp32 VALU) ----------------
__global__ __launch_bounds__(256) void k_convom(const float* __restrict__ x,
                                                const float* __restrict__ w_off,
                                                const float* __restrict__ b_off,
                                                const float* __restrict__ w_mask,
                                                const float* __restrict__ b_mask,
                                                float* __restrict__ off_out,
                                                float* __restrict__ mask_out) {
  __shared__ float wlds[27 * 576];   // 62,208 B
  for (int i = threadIdx.x; i < 18 * 576; i += 256) wlds[i] = w_off[i];
  for (int i = threadIdx.x; i < 9 * 576; i += 256) wlds[18 * 576 + i] = w_mask[i];
  __syncthreads();

  int t = blockIdx.x * 256 + threadIdx.x;  // 65536 threads, 2 px each
  int pix = t * 2;
  int b = pix / HWHW;
  int hw = pix % HWHW;
  int y = hw / WW;
  int x0 = hw % WW;                        // even, pair stays in row

  float acc[27][2];
#pragma unroll
  for (int ch = 0; ch < 27; ++ch) { acc[ch][0] = 0.f; acc[ch][1] = 0.f; }

  const float* xb = x + (size_t)b * CC * HWHW;
  for (int c = 0; c < CC; ++c) {
    float xv[3][4];
#pragma unroll
    for (int r = 0; r < 3; ++r) {
      int yy = y + r - 1;
      bool yok = ((unsigned)yy < (unsigned)HH);
      const float* rowp = xb + c * HWHW + yy * WW;
#pragma unroll
      for (int q = 0; q < 4; ++q) {
        int xx = x0 + q - 1;
        bool ok = yok && ((unsigned)xx < (unsigned)WW);
        xv[r][q] = ok ? rowp[xx] : 0.f;
      }
    }
    const float* wc = &wlds[c * 9];
#pragma unroll
    for (int ch = 0; ch < 27; ++ch) {
      const float* wp = wc + ch * 576;
#pragma unroll
      for (int r = 0; r < 3; ++r) {
#pragma unroll
        for (int q = 0; q < 3; ++q) {
          float wv = wp[r * 3 + q];
          acc[ch][0] += xv[r][q] * wv;
          acc[ch][1] += xv[r][q + 1] * wv;
        }
      }
    }
  }

  int base_off = b * 18 * HWHW + y * WW + x0;
#pragma unroll
  for (int ch = 0; ch < 18; ++ch) {
    float bb = b_off[ch];
    off_out[base_off + ch * HWHW] = acc[ch][0] + bb;
    off_out[base_off + ch * HWHW + 1] = acc[ch][1] + bb;
  }
  int base_m = b * 9 * HWHW + y * WW + x0;
#pragma unroll
  for (int ch = 0; ch < 9; ++ch) {
    float bb = b_mask[ch];
    float v0 = acc[18 + ch][0] + bb;
    float v1 = acc[18 + ch][1] + bb;
    mask_out[base_m + ch * HWHW] = 1.f / (1.f + expf(-v0));
    mask_out[base_m + ch * HWHW + 1] = 1.f / (1.f + expf(-v1));
  }
}

// ---------------- Kernel 4: deformable conv — bf16 gather + MFMA ----------------
// Block = 256 thr (4 waves), 16 consecutive-x pixels (one row).
// Phase 1: wave gathers 4 px x 9 taps, lane=channel, branch-free bilinear,
//          writes bf16 to LDS cols[16][CSTR].
// Phase 2: wave w owns out-channels w*16..w*16+15; 18 K-steps of
//          mfma_f32_16x16x32_bf16 with A from LDS, B from global bf16 w.
// NOTE: __launch_bounds__(256,4): round-2's (256,8) capped VGPR at 32 ->
// scratch spill -> 4.2 GB HBM traffic. 128-VGPR cap fits spill-free.
#define CSTR 584   // padded row stride in bf16 elems (584*2 B = 73*16 B)
__global__ __launch_bounds__(256, 4) void k_deform(const float* __restrict__ xt,
                                                   const float* __restrict__ off,
                                                   const float* __restrict__ msk,
                                                   const unsigned short* __restrict__ wbf,
                                                   float* __restrict__ out) {
  __shared__ unsigned short cols[16 * CSTR];  // 18,688 B
  int blk = blockIdx.x;          // 8192 blocks
  int pix0 = blk * 16;
  int b = pix0 / HWHW;
  int hw0 = pix0 % HWHW;
  int y = hw0 / WW;
  int x0 = hw0 % WW;             // 16 consecutive x in one row
  int wave = threadIdx.x >> 6;
  int lane = threadIdx.x & 63;   // = input channel c in phase 1
  const float* xb = xt + (size_t)b * HWHW * 64;

#pragma unroll
  for (int pp = 0; pp < 4; ++pp) {
    int p = wave * 4 + pp;
    int xx = x0 + p;
    const float* offp = off + (size_t)b * 18 * HWHW + y * WW + xx;
    const float* mp = msk + (size_t)b * 9 * HWHW + y * WW + xx;
#pragma unroll
    for (int k = 0; k < 9; ++k) {
      float dy = offp[(2 * k) * HWHW];
      float dx = offp[(2 * k + 1) * HWHW];
      float m = mp[k * HWHW];
      float py = (float)(y + k / 3 - 1) + dy;
      float px = (float)(xx + k % 3 - 1) + dx;
      float fy = floorf(py);
      float fx = floorf(px);
      int y0i = (int)fy;
      int x0i = (int)fx;
      float wy1 = py - fy;
      float wx1 = px - fx;
      float wy0 = 1.f - wy1;
      float wx0 = 1.f - wx1;
      // validity as multiplicative flags (branch-free)
      float vy0 = ((unsigned)y0i < (unsigned)HH) ? 1.f : 0.f;
      float vy1 = ((unsigned)(y0i + 1) < (unsigned)HH) ? 1.f : 0.f;
      float vx0 = ((unsigned)x0i < (unsigned)WW) ? 1.f : 0.f;
      float vx1 = ((unsigned)(x0i + 1) < (unsigned)WW) ? 1.f : 0.f;
      int y0c = min(max(y0i, 0), HH - 1);
      int y1c = min(max(y0i + 1, 0), HH - 1);
      int x0c = min(max(x0i, 0), WW - 1);
      int x1c = min(max(x0i + 1, 0), WW - 1);
      const float* r0 = xb + (size_t)(y0c * WW) * 64 + lane;
      const float* r1 = xb + (size_t)(y1c * WW) * 64 + lane;
      float v00 = r0[x0c * 64];
      float v01 = r0[x1c * 64];
      float v10 = r1[x0c * 64];
      float v11 = r1[x1c * 64];
      float w00 = wy0 * wx0 * vy0 * vx0;
      float w01 = wy0 * wx1 * vy0 * vx1;
      float w10 = wy1 * wx0 * vy1 * vx0;
      float w11 = wy1 * wx1 * vy1 * vx1;
      float val = (v00 * w00 + v01 * w01 + v10 * w10 + v11 * w11) * m;
      __hip_bfloat16 h = __float2bfloat16(val);
      cols[p * CSTR + lane * 9 + k] = *(unsigned short*)&h;
    }
  }
  __syncthreads();

  // Phase 2: MFMA. A[m][k] = cols[m][k] (pixels x 576), B[k][n] = w[n][k].
  int mrow = lane & 15;        // A row (pixel) for A-frag; B col (o) for B-frag
  int kgrp = lane >> 4;        // k sub-group 0..3
  int otile = wave * 16;
  f32x4 acc = {0.f, 0.f, 0.f, 0.f};
  const unsigned short* wp = wbf + (size_t)(otile + mrow) * 576 + kgrp * 8;
  const unsigned short* cp = &cols[mrow * CSTR + kgrp * 8];
#pragma unroll
  for (int s = 0; s < 18; ++s) {
    bf16x8 a = *(const bf16x8*)(cp + s * 32);
    bf16x8 bb = *(const bf16x8*)(wp + s * 32);
    acc = __builtin_amdgcn_mfma_f32_16x16x32_bf16(a, bb, acc, 0, 0, 0);
  }
  // C/D layout: lane holds D[row=(lane>>4)*4+r][col=lane&15]; row=pixel, col=o.
  int o = otile + mrow;
  float* op = out + (size_t)(b * 64 + o) * HWHW + y * WW + x0 + kgrp * 4;
  *(f32x4*)op = acc;
}

extern "C" void kernel_launch(void* const* d_in, const int* in_sizes, int n_in,
                              void* d_out, int out_size, void* d_ws, size_t ws_size,
                              hipStream_t stream) {
  const float* x = (const float*)d_in[0];
  const float* w_off = (const float*)d_in[1];
  const float* b_off = (const float*)d_in[2];
  const float* w_mask = (const float*)d_in[3];
  const float* b_mask = (const float*)d_in[4];
  const float* w_dcn = (const float*)d_in[5];
  float* out = (float*)d_out;

  char* ws = (char*)d_ws;
  float* xt = (float*)ws;                                  // 33,554,432 B
  float* off = (float*)(ws + 33554432);                    //  9,437,184 B
  float* msk = (float*)(ws + 33554432 + 9437184);          //  4,718,592 B
  unsigned short* wbf = (unsigned short*)(ws + 33554432 + 9437184 + 4718592); // 73,728 B

  hipLaunchKernelGGL(k_transpose, dim3(2048), dim3(256), 0, stream, x, xt);
  hipLaunchKernelGGL(k_wcast, dim3(144), dim3(256), 0, stream, w_dcn, wbf);
  hipLaunchKernelGGL(k_convom, dim3(256), dim3(256), 0, stream, x, w_off, b_off,
                     w_mask, b_mask, off, msk);
  hipLaunchKernelGGL(k_deform, dim3(8192), dim3(256), 0, stream, xt, off, msk, wbf, out);
}

// Round 4
// 330.942 us; speedup vs baseline: 3.7918x; 1.4771x over previous
//
#include <hip/hip_runtime.h>
#include <hip/hip_bf16.h>
#include <math.h>

#define BB 8
#define CC 64
#define HH 128
#define WW 128
#define OO 64
#define HWHW (HH*WW)

typedef short bf16x8 __attribute__((ext_vector_type(8)));
typedef float f32x4 __attribute__((ext_vector_type(4)));

// ---------------- Kernel 1: NCHW -> NHWC transpose of x ----------------
__global__ __launch_bounds__(256) void k_transpose(const float* __restrict__ x,
                                                   float* __restrict__ xt) {
  __shared__ float tile[64][65];
  int blk = blockIdx.x;            // 2048 blocks: 8 batches * 256 hw-chunks
  int b = blk >> 8;
  int hw0 = (blk & 255) << 6;      // 64 hw positions per block
  int lane = threadIdx.x & 63;
  int g = threadIdx.x >> 6;        // 0..3
  const float* xb = x + (size_t)b * CC * HWHW;
#pragma unroll
  for (int i = 0; i < 16; ++i) {
    int c = g + i * 4;
    tile[lane][c] = xb[c * HWHW + hw0 + lane];   // coalesced read along hw
  }
  __syncthreads();
  float* xtb = xt + (size_t)b * HWHW * CC;
#pragma unroll
  for (int j = 0; j < 16; ++j) {
    int hwl = g + j * 4;
    xtb[(size_t)(hw0 + hwl) * 64 + lane] = tile[hwl][lane];  // coalesced along c
  }
}

// ---------------- Kernel 2: cast+permute w_dcn: [O][c*9+k] fp32 -> [O][k*64+c] bf16 ----
// K-ordering k*64+c makes k_deform's phase-1 LDS writes conflict-free.
__global__ __launch_bounds__(256) void k_wcast(const float* __restrict__ w,
                                               unsigned short* __restrict__ wbf) {
  int i = blockIdx.x * 256 + threadIdx.x;  // 36864 elements, coalesced read
  int o = i / 576;
  int ck = i % 576;
  int c = ck / 9;
  int kk = ck % 9;
  __hip_bfloat16 h = __float2bfloat16(w[i]);
  wbf[o * 576 + kk * 64 + c] = *(unsigned short*)&h;
}

// ---------------- Kernel 3: fused offset+mask 3x3 conv (fp32 VALU) ----------------
__global__ __launch_bounds__(256) void k_convom(const float* __restrict__ x,
                                                const float* __restrict__ w_off,
                                                const float* __restrict__ b_off,
                                                const float* __restrict__ w_mask,
                                                const float* __restrict__ b_mask,
                                                float* __restrict__ off_out,
                                                float* __restrict__ mask_out) {
  __shared__ float wlds[27 * 576];   // 62,208 B
  for (int i = threadIdx.x; i < 18 * 576; i += 256) wlds[i] = w_off[i];
  for (int i = threadIdx.x; i < 9 * 576; i += 256) wlds[18 * 576 + i] = w_mask[i];
  __syncthreads();

  int t = blockIdx.x * 256 + threadIdx.x;  // 65536 threads, 2 px each
  int pix = t * 2;
  int b = pix / HWHW;
  int hw = pix % HWHW;
  int y = hw / WW;
  int x0 = hw % WW;                        // even, pair stays in row

  float acc[27][2];
#pragma unroll
  for (int ch = 0; ch < 27; ++ch) { acc[ch][0] = 0.f; acc[ch][1] = 0.f; }

  const float* xb = x + (size_t)b * CC * HWHW;
  for (int c = 0; c < CC; ++c) {
    float xv[3][4];
#pragma unroll
    for (int r = 0; r < 3; ++r) {
      int yy = y + r - 1;
      bool yok = ((unsigned)yy < (unsigned)HH);
      const float* rowp = xb + c * HWHW + yy * WW;
#pragma unroll
      for (int q = 0; q < 4; ++q) {
        int xx = x0 + q - 1;
        bool ok = yok && ((unsigned)xx < (unsigned)WW);
        xv[r][q] = ok ? rowp[xx] : 0.f;
      }
    }
    const float* wc = &wlds[c * 9];
#pragma unroll
    for (int ch = 0; ch < 27; ++ch) {
      const float* wp = wc + ch * 576;
#pragma unroll
      for (int r = 0; r < 3; ++r) {
#pragma unroll
        for (int q = 0; q < 3; ++q) {
          float wv = wp[r * 3 + q];
          acc[ch][0] += xv[r][q] * wv;
          acc[ch][1] += xv[r][q + 1] * wv;
        }
      }
    }
  }

  int base_off = b * 18 * HWHW + y * WW + x0;
#pragma unroll
  for (int ch = 0; ch < 18; ++ch) {
    float bb = b_off[ch];
    off_out[base_off + ch * HWHW] = acc[ch][0] + bb;
    off_out[base_off + ch * HWHW + 1] = acc[ch][1] + bb;
  }
  int base_m = b * 9 * HWHW + y * WW + x0;
#pragma unroll
  for (int ch = 0; ch < 9; ++ch) {
    float bb = b_mask[ch];
    float v0 = acc[18 + ch][0] + bb;
    float v1 = acc[18 + ch][1] + bb;
    mask_out[base_m + ch * HWHW] = 1.f / (1.f + expf(-v0));
    mask_out[base_m + ch * HWHW + 1] = 1.f / (1.f + expf(-v1));
  }
}

// ---------------- Kernel 4: deformable conv — bf16 gather + MFMA ----------------
// Block = 256 thr (4 waves), 16 consecutive-x pixels (one row).
// Phase 1: wave gathers 4 px x 9 taps, lane=channel, branch-free bilinear,
//          writes bf16 to LDS cols[16][CSTR] with K-index k*64+c
//          (64 lanes x 2B consecutive per (p,k) -> conflict-free).
// Phase 2: wave w owns out-channels w*16..w*16+15; 18 K-steps of
//          mfma_f32_16x16x32_bf16 with A from LDS, B from global bf16 w
//          (same k*64+c K-ordering via k_wcast).
// NOTE: no min-waves bound. (256,8)->VGPR32 and (256,4)->VGPR64 both spilled
// (2.0 GB / 0.8 GB excess HBM writes). Compiler-chosen VGPR is spill-free.
#define CSTR 584   // padded row stride: 1168 B -> +4 banks/row on A-frag reads
__global__ __launch_bounds__(256) void k_deform(const float* __restrict__ xt,
                                                const float* __restrict__ off,
                                                const float* __restrict__ msk,
                                                const unsigned short* __restrict__ wbf,
                                                float* __restrict__ out) {
  __shared__ unsigned short cols[16 * CSTR];  // 18,688 B
  int blk = blockIdx.x;          // 8192 blocks
  int pix0 = blk * 16;
  int b = pix0 / HWHW;
  int hw0 = pix0 % HWHW;
  int y = hw0 / WW;
  int x0 = hw0 % WW;             // 16 consecutive x in one row
  int wave = threadIdx.x >> 6;
  int lane = threadIdx.x & 63;   // = input channel c in phase 1
  const float* xb = xt + (size_t)b * HWHW * 64;

#pragma unroll
  for (int pp = 0; pp < 4; ++pp) {
    int p = wave * 4 + pp;
    int xx = x0 + p;
    const float* offp = off + (size_t)b * 18 * HWHW + y * WW + xx;
    const float* mp = msk + (size_t)b * 9 * HWHW + y * WW + xx;
    unsigned short* colp = &cols[p * CSTR];
#pragma unroll
    for (int k = 0; k < 9; ++k) {
      float dy = offp[(2 * k) * HWHW];
      float dx = offp[(2 * k + 1) * HWHW];
      float m = mp[k * HWHW];
      float py = (float)(y + k / 3 - 1) + dy;
      float px = (float)(xx + k % 3 - 1) + dx;
      float fy = floorf(py);
      float fx = floorf(px);
      int y0i = (int)fy;
      int x0i = (int)fx;
      float wy1 = py - fy;
      float wx1 = px - fx;
      float wy0 = 1.f - wy1;
      float wx0 = 1.f - wx1;
      // validity as multiplicative flags (branch-free)
      float vy0 = ((unsigned)y0i < (unsigned)HH) ? 1.f : 0.f;
      float vy1 = ((unsigned)(y0i + 1) < (unsigned)HH) ? 1.f : 0.f;
      float vx0 = ((unsigned)x0i < (unsigned)WW) ? 1.f : 0.f;
      float vx1 = ((unsigned)(x0i + 1) < (unsigned)WW) ? 1.f : 0.f;
      int y0c = min(max(y0i, 0), HH - 1);
      int y1c = min(max(y0i + 1, 0), HH - 1);
      int x0c = min(max(x0i, 0), WW - 1);
      int x1c = min(max(x0i + 1, 0), WW - 1);
      const float* r0 = xb + (size_t)(y0c * WW) * 64 + lane;
      const float* r1 = xb + (size_t)(y1c * WW) * 64 + lane;
      float v00 = r0[x0c * 64];
      float v01 = r0[x1c * 64];
      float v10 = r1[x0c * 64];
      float v11 = r1[x1c * 64];
      float w00 = wy0 * wx0 * vy0 * vx0;
      float w01 = wy0 * wx1 * vy0 * vx1;
      float w10 = wy1 * wx0 * vy1 * vx0;
      float w11 = wy1 * wx1 * vy1 * vx1;
      float val = (v00 * w00 + v01 * w01 + v10 * w10 + v11 * w11) * m;
      __hip_bfloat16 h = __float2bfloat16(val);
      colp[k * 64 + lane] = *(unsigned short*)&h;   // conflict-free b16 write
    }
  }
  __syncthreads();

  // Phase 2: MFMA. A[m][kidx] = cols[m][kidx], B[kidx][n] = wbf[n][kidx],
  // kidx = k*64+c (consistent on both sides).
  int mrow = lane & 15;        // A row (pixel); also B col (o)
  int kgrp = lane >> 4;        // k sub-group 0..3
  int otile = wave * 16;
  f32x4 acc = {0.f, 0.f, 0.f, 0.f};
  const unsigned short* wp = wbf + (size_t)(otile + mrow) * 576 + kgrp * 8;
  const unsigned short* cp = &cols[mrow * CSTR + kgrp * 8];
#pragma unroll
  for (int s = 0; s < 18; ++s) {
    bf16x8 a = *(const bf16x8*)(cp + s * 32);
    bf16x8 bb = *(const bf16x8*)(wp + s * 32);
    acc = __builtin_amdgcn_mfma_f32_16x16x32_bf16(a, bb, acc, 0, 0, 0);
  }
  // C/D layout: lane holds D[row=(lane>>4)*4+r][col=lane&15]; row=pixel, col=o.
  int o = otile + mrow;
  float* op = out + (size_t)(b * 64 + o) * HWHW + y * WW + x0 + kgrp * 4;
  *(f32x4*)op = acc;
}

extern "C" void kernel_launch(void* const* d_in, const int* in_sizes, int n_in,
                              void* d_out, int out_size, void* d_ws, size_t ws_size,
                              hipStream_t stream) {
  const float* x = (const float*)d_in[0];
  const float* w_off = (const float*)d_in[1];
  const float* b_off = (const float*)d_in[2];
  const float* w_mask = (const float*)d_in[3];
  const float* b_mask = (const float*)d_in[4];
  const float* w_dcn = (const float*)d_in[5];
  float* out = (float*)d_out;

  char* ws = (char*)d_ws;
  float* xt = (float*)ws;                                  // 33,554,432 B
  float* off = (float*)(ws + 33554432);                    //  9,437,184 B
  float* msk = (float*)(ws + 33554432 + 9437184);          //  4,718,592 B
  unsigned short* wbf = (unsigned short*)(ws + 33554432 + 9437184 + 4718592); // 73,728 B

  hipLaunchKernelGGL(k_transpose, dim3(2048), dim3(256), 0, stream, x, xt);
  hipLaunchKernelGGL(k_wcast, dim3(144), dim3(256), 0, stream, w_dcn, wbf);
  hipLaunchKernelGGL(k_convom, dim3(256), dim3(256), 0, stream, x, w_off, b_off,
                     w_mask, b_mask, off, msk);
  hipLaunchKernelGGL(k_deform, dim3(8192), dim3(256), 0, stream, xt, off, msk, wbf, out);
}

// Round 5
// 196.542 us; speedup vs baseline: 6.3848x; 1.6838x over previous
//
#include <hip/hip_runtime.h>
#include <hip/hip_bf16.h>
#include <math.h>

#define BB 8
#define CC 64
#define HH 128
#define WW 128
#define OO 64
#define HWHW (HH*WW)

typedef short bf16x8 __attribute__((ext_vector_type(8)));
typedef float f32x4 __attribute__((ext_vector_type(4)));
typedef unsigned short ushort_t;

__device__ __forceinline__ float bf2f(ushort_t u) {
  unsigned v = ((unsigned)u) << 16;
  return __builtin_bit_cast(float, v);
}
__device__ __forceinline__ ushort_t f2bf(float f) {
  __hip_bfloat16 h = __float2bfloat16(f);
  return *(ushort_t*)&h;
}

// ---------------- Kernel 1: NCHW fp32 -> NHWC bf16 transpose of x ----------------
__global__ __launch_bounds__(256) void k_transpose(const float* __restrict__ x,
                                                   ushort_t* __restrict__ xt) {
  __shared__ float tile[64][65];
  int blk = blockIdx.x;            // 2048 blocks: 8 batches * 256 hw-chunks
  int b = blk >> 8;
  int hw0 = (blk & 255) << 6;      // 64 hw positions per block
  int lane = threadIdx.x & 63;
  int g = threadIdx.x >> 6;        // 0..3
  const float* xb = x + (size_t)b * CC * HWHW;
#pragma unroll
  for (int i = 0; i < 16; ++i) {
    int c = g + i * 4;
    tile[lane][c] = xb[c * HWHW + hw0 + lane];   // coalesced read along hw
  }
  __syncthreads();
  ushort_t* xtb = xt + (size_t)b * HWHW * 64;
#pragma unroll
  for (int j = 0; j < 16; ++j) {
    int hwl = g + j * 4;
    xtb[(size_t)(hw0 + hwl) * 64 + lane] = f2bf(tile[hwl][lane]);  // coalesced along c
  }
}

// ---------------- Kernel 2: weight prep ----------------
// wbf:  w_dcn [O][c*9+t] fp32 -> [O][t*64+c] bf16   (36864 elems)
// w_om: rows 0..17 = w_off, 18..26 = w_mask, 27..31 = 0; [32][t*64+c] bf16 (18432)
__global__ __launch_bounds__(256) void k_wcast(const float* __restrict__ w_dcn,
                                               const float* __restrict__ w_off,
                                               const float* __restrict__ w_mask,
                                               ushort_t* __restrict__ wbf,
                                               ushort_t* __restrict__ w_om) {
  int i = blockIdx.x * 256 + threadIdx.x;   // 216 blocks * 256 = 55296
  if (i < 36864) {
    int o = i / 576;
    int ck = i % 576;
    int c = ck / 9;
    int t = ck % 9;
    wbf[o * 576 + t * 64 + c] = f2bf(w_dcn[i]);
  } else {
    int j = i - 36864;          // 0..18431
    int o = j / 576;
    int r = j % 576;
    int t = r / 64;
    int c = r % 64;
    float v = 0.f;
    if (o < 18) v = w_off[o * 576 + c * 9 + t];
    else if (o < 27) v = w_mask[(o - 18) * 576 + c * 9 + t];
    w_om[j] = f2bf(v);
  }
}

// ---------------- Kernel 3: fused offset-conv + deformable conv ----------------
// Block = 256 thr (4 waves), 16 consecutive-x pixels (one row).
// A: stage xtile[3][18][XST] bf16 (halo-padded row triple).
// B: waves 0,1: offset/mask conv via 18 MFMA vs w_om -> offm[32][16] (sigmoid on mask).
// C: 144 threads precompute per-tap {4 weights, 4 base addrs}; then all 4 waves
//    gather (lane=channel): 4 coalesced ushort loads + 4 FMA per tap -> bf16 cols.
// D: waves own 16 out-channels each; 18 MFMA vs wbf -> out (NCHW, float4 stores).
#define CSTR 584   // cols row stride (bf16): 1168 B = 73*16 -> +4 banks/row
#define XST 72     // xtile inner stride (bf16): 144 B, 16B-aligned
__global__ __launch_bounds__(256) void k_deform(const ushort_t* __restrict__ xtbf,
                                                const ushort_t* __restrict__ w_om,
                                                const float* __restrict__ b_off,
                                                const float* __restrict__ b_mask,
                                                const ushort_t* __restrict__ wbf,
                                                float* __restrict__ out) {
  // LDS: [0,7808) xtile (aliased by tap tables after conv) | [7808,9856) offm
  //      | [9856,28544) cols
  __shared__ __align__(16) unsigned char smem[28544];
  ushort_t (*xtile)[18][XST] = (ushort_t(*)[18][XST])smem;   // 3*18*72*2 = 7776 B
  float (*tapw)[4] = (float(*)[4])smem;                      // 144*16 = 2304 B
  int   (*tapa)[4] = (int(*)[4])(smem + 2304);               // 2304 B
  float (*offm)[16] = (float(*)[16])(smem + 7808);           // 32*16*4 = 2048 B
  ushort_t* cols = (ushort_t*)(smem + 9856);                 // 16*584*2 = 18688 B

  int blk = blockIdx.x;          // 8192 blocks
  int pix0 = blk * 16;
  int b = pix0 / HWHW;
  int hw0 = pix0 % HWHW;
  int y = hw0 / WW;
  int x0 = hw0 % WW;             // 16 consecutive x in one row
  int wave = threadIdx.x >> 6;
  int lane = threadIdx.x & 63;   // = input channel c in staging/gather
  int tid = threadIdx.x;
  const ushort_t* xbu = xtbf + (size_t)b * HWHW * 64;

  // ---- Phase A: stage halo tile ----
#pragma unroll
  for (int ry = 0; ry < 3; ++ry) {
    int yy = y + ry - 1;
    bool yok = ((unsigned)yy < (unsigned)HH);
    for (int xi = wave; xi < 18; xi += 4) {
      int xx = x0 + xi - 1;
      bool ok = yok && ((unsigned)xx < (unsigned)WW);
      ushort_t v = 0;
      if (ok) v = xbu[(size_t)(yy * WW + xx) * 64 + lane];
      xtile[ry][xi][lane] = v;
    }
  }
  __syncthreads();

  // ---- Phase B: offset/mask conv (waves 0,1) ----
  if (wave < 2) {
    int mr = lane & 15;          // A pixel-row AND B o-row
    int kg = lane >> 4;
    f32x4 cacc = {0.f, 0.f, 0.f, 0.f};
    const ushort_t* wrow = w_om + (size_t)(wave * 16 + mr) * 576 + kg * 8;
#pragma unroll
    for (int s = 0; s < 18; ++s) {
      int t = s >> 1;
      int coff = (s & 1) * 32;
      int ky = t / 3, kx = t % 3;              // compile-time
      bf16x8 a = *(const bf16x8*)&xtile[ky][mr + kx][coff + kg * 8];
      bf16x8 bb = *(const bf16x8*)(wrow + s * 32);
      cacc = __builtin_amdgcn_mfma_f32_16x16x32_bf16(a, bb, cacc, 0, 0, 0);
    }
    int o = wave * 16 + mr;
    float bias = 0.f;
    if (o < 18) bias = b_off[o];
    else if (o < 27) bias = b_mask[o - 18];
    bool is_mask = (o >= 18) && (o < 27);
#pragma unroll
    for (int r = 0; r < 4; ++r) {
      float v = cacc[r] + bias;
      if (is_mask) v = 1.f / (1.f + expf(-v));
      cacc[r] = v;
    }
    *(f32x4*)&offm[o][kg * 4] = cacc;   // D rows = pixels kg*4..kg*4+3
  }
  __syncthreads();

  // ---- Phase C1: per-tap setup (threads 0..143) ----
  if (tid < 144) {
    int p = tid / 9;
    int k = tid - p * 9;
    float dy = offm[2 * k][p];
    float dx = offm[2 * k + 1][p];
    float m = offm[18 + k][p];
    int xx = x0 + p;
    float py = (float)(y + k / 3 - 1) + dy;
    float pxf = (float)(xx + k % 3 - 1) + dx;
    float fy = floorf(py), fx = floorf(pxf);
    int y0i = (int)fy, x0i = (int)fx;
    float wy1 = py - fy, wx1 = pxf - fx;
    float wy0 = 1.f - wy1, wx0 = 1.f - wx1;
    float vy0 = ((unsigned)y0i < (unsigned)HH) ? 1.f : 0.f;
    float vy1 = ((unsigned)(y0i + 1) < (unsigned)HH) ? 1.f : 0.f;
    float vx0 = ((unsigned)x0i < (unsigned)WW) ? 1.f : 0.f;
    float vx1 = ((unsigned)(x0i + 1) < (unsigned)WW) ? 1.f : 0.f;
    int y0c = min(max(y0i, 0), HH - 1);
    int y1c = min(max(y0i + 1, 0), HH - 1);
    int x0c = min(max(x0i, 0), WW - 1);
    int x1c = min(max(x0i + 1, 0), WW - 1);
    tapw[tid][0] = wy0 * wx0 * vy0 * vx0 * m;
    tapw[tid][1] = wy0 * wx1 * vy0 * vx1 * m;
    tapw[tid][2] = wy1 * wx0 * vy1 * vx0 * m;
    tapw[tid][3] = wy1 * wx1 * vy1 * vx1 * m;
    tapa[tid][0] = (y0c * WW + x0c) * 64;
    tapa[tid][1] = (y0c * WW + x1c) * 64;
    tapa[tid][2] = (y1c * WW + x0c) * 64;
    tapa[tid][3] = (y1c * WW + x1c) * 64;
  }
  __syncthreads();

  // ---- Phase C2: gather (all waves; lane = channel) ----
#pragma unroll
  for (int pp = 0; pp < 4; ++pp) {
    int p = wave * 4 + pp;
    ushort_t* colp = cols + p * CSTR;
    int tb = p * 9;
#pragma unroll
    for (int k = 0; k < 9; ++k) {
      f32x4 w4 = *(const f32x4*)tapw[tb + k];   // wave-uniform broadcast
      int4 a4 = *(const int4*)tapa[tb + k];
      float f00 = bf2f(xbu[a4.x + lane]);
      float f01 = bf2f(xbu[a4.y + lane]);
      float f10 = bf2f(xbu[a4.z + lane]);
      float f11 = bf2f(xbu[a4.w + lane]);
      float val = f00 * w4.x + f01 * w4.y + f10 * w4.z + f11 * w4.w;
      colp[k * 64 + lane] = f2bf(val);
    }
  }
  __syncthreads();

  // ---- Phase D: main GEMM (cols[16][576] x wbf[64][576]^T) ----
  int mrow = lane & 15;        // A pixel-row AND B o-row
  int kgrp = lane >> 4;
  int otile = wave * 16;
  f32x4 acc = {0.f, 0.f, 0.f, 0.f};
  const ushort_t* wp = wbf + (size_t)(otile + mrow) * 576 + kgrp * 8;
  const ushort_t* cp = &cols[mrow * CSTR + kgrp * 8];
#pragma unroll
  for (int s = 0; s < 18; ++s) {
    bf16x8 a = *(const bf16x8*)(cp + s * 32);
    bf16x8 bb = *(const bf16x8*)(wp + s * 32);
    acc = __builtin_amdgcn_mfma_f32_16x16x32_bf16(a, bb, acc, 0, 0, 0);
  }
  // D: lane holds out[px=kgrp*4+r][o=otile+mrow], 4 consecutive px -> float4 store
  int o = otile + mrow;
  float* op = out + (size_t)(b * 64 + o) * HWHW + y * WW + x0 + kgrp * 4;
  *(f32x4*)op = acc;
}

extern "C" void kernel_launch(void* const* d_in, const int* in_sizes, int n_in,
                              void* d_out, int out_size, void* d_ws, size_t ws_size,
                              hipStream_t stream) {
  const float* x = (const float*)d_in[0];
  const float* w_off = (const float*)d_in[1];
  const float* b_off = (const float*)d_in[2];
  const float* w_mask = (const float*)d_in[3];
  const float* b_mask = (const float*)d_in[4];
  const float* w_dcn = (const float*)d_in[5];
  float* out = (float*)d_out;

  char* ws = (char*)d_ws;
  ushort_t* xtbf = (ushort_t*)ws;                         // 16,777,216 B
  ushort_t* wbf = (ushort_t*)(ws + 16777216);             //     73,728 B
  ushort_t* w_om = (ushort_t*)(ws + 16777216 + 73728);    //     36,864 B

  hipLaunchKernelGGL(k_transpose, dim3(2048), dim3(256), 0, stream, x, xtbf);
  hipLaunchKernelGGL(k_wcast, dim3(216), dim3(256), 0, stream, w_dcn, w_off, w_mask,
                     wbf, w_om);
  hipLaunchKernelGGL(k_deform, dim3(8192), dim3(256), 0, stream, xtbf, w_om,
                     b_off, b_mask, wbf, out);
}

// Round 6
// 171.972 us; speedup vs baseline: 7.2970x; 1.1429x over previous
//
#include <hip/hip_runtime.h>
#include <hip/hip_bf16.h>
#include <math.h>

#define BB 8
#define CC 64
#define HH 128
#define WW 128
#define OO 64
#define HWHW (HH*WW)

typedef short bf16x8 __attribute__((ext_vector_type(8)));
typedef float f32x4 __attribute__((ext_vector_type(4)));
typedef unsigned short ushort_t;

__device__ __forceinline__ float bf2f(ushort_t u) {
  unsigned v = ((unsigned)u) << 16;
  return __builtin_bit_cast(float, v);
}
__device__ __forceinline__ ushort_t f2bf(float f) {
  __hip_bfloat16 h = __float2bfloat16(f);
  return *(ushort_t*)&h;
}

// ---------------- Kernel 1: NCHW fp32 -> NHWC bf16 transpose of x ----------------
__global__ __launch_bounds__(256) void k_transpose(const float* __restrict__ x,
                                                   ushort_t* __restrict__ xt) {
  __shared__ float tile[64][65];
  int blk = blockIdx.x;            // 2048 blocks: 8 batches * 256 hw-chunks
  int b = blk >> 8;
  int hw0 = (blk & 255) << 6;      // 64 hw positions per block
  int lane = threadIdx.x & 63;
  int g = threadIdx.x >> 6;        // 0..3
  const float* xb = x + (size_t)b * CC * HWHW;
#pragma unroll
  for (int i = 0; i < 16; ++i) {
    int c = g + i * 4;
    tile[lane][c] = xb[c * HWHW + hw0 + lane];   // coalesced read along hw
  }
  __syncthreads();
  ushort_t* xtb = xt + (size_t)b * HWHW * 64;
#pragma unroll
  for (int j = 0; j < 16; ++j) {
    int hwl = g + j * 4;
    xtb[(size_t)(hw0 + hwl) * 64 + lane] = f2bf(tile[hwl][lane]);  // coalesced along c
  }
}

// ---------------- Kernel 2: weight prep ----------------
// wbf:  w_dcn [O][c*9+t] fp32 -> [O][t*64+c] bf16   (36864 elems)
// w_om: rows 0..17 = w_off, 18..26 = w_mask, 27..31 = 0; [32][t*64+c] bf16 (18432)
__global__ __launch_bounds__(256) void k_wcast(const float* __restrict__ w_dcn,
                                               const float* __restrict__ w_off,
                                               const float* __restrict__ w_mask,
                                               ushort_t* __restrict__ wbf,
                                               ushort_t* __restrict__ w_om) {
  int i = blockIdx.x * 256 + threadIdx.x;   // 216 blocks * 256 = 55296
  if (i < 36864) {
    int o = i / 576;
    int ck = i % 576;
    int c = ck / 9;
    int t = ck % 9;
    wbf[o * 576 + t * 64 + c] = f2bf(w_dcn[i]);
  } else {
    int j = i - 36864;          // 0..18431
    int o = j / 576;
    int r = j % 576;
    int t = r / 64;
    int c = r % 64;
    float v = 0.f;
    if (o < 18) v = w_off[o * 576 + c * 9 + t];
    else if (o < 27) v = w_mask[(o - 18) * 576 + c * 9 + t];
    w_om[j] = f2bf(v);
  }
}

// ---------------- Kernel 3: fused offset-conv + deformable conv ----------------
// Block = 256 thr (4 waves), 16 consecutive-x pixels (one row).
// A: stage xtile[3][18][XST] bf16 (halo-padded row triple).
// B: waves 0,1: offset/mask conv via 18 MFMA vs w_om -> offm[32][16] (sigmoid on mask).
// C1: 144 threads precompute per-tap {4 premult weights, 4 corner base offsets}.
// C2: gather, corner-pair split: lanes 0-31 = corners {00,01}, lanes 32-63 =
//     {10,11}, dword loads (2 channels/lane), cross-half __shfl_xor combine.
//     All 9 taps batched: tables -> 18 loads -> compute (ILP by construction).
// D: waves own 16 out-channels each; 18 MFMA vs wbf -> out (NCHW, float4 stores).
// __launch_bounds__(256,3): VGPR cap ~85 fits the ~75 live regs of the batched
// gather spill-free (r2/r3: caps 32/64 spilled; r5: default squeezed to 48 and
// serialized the taps).
#define CSTR 584   // cols row stride (bf16): 1168 B = 73*16 -> +4 banks/row
#define XST 72     // xtile inner stride (bf16): 144 B, 16B-aligned
__global__ __launch_bounds__(256, 3) void k_deform(const ushort_t* __restrict__ xtbf,
                                                   const ushort_t* __restrict__ w_om,
                                                   const float* __restrict__ b_off,
                                                   const float* __restrict__ b_mask,
                                                   const ushort_t* __restrict__ wbf,
                                                   float* __restrict__ out) {
  // LDS: [0,7808) xtile (aliased by tap tables after conv) | [7808,9856) offm
  //      | [9856,28544) cols
  __shared__ __align__(16) unsigned char smem[28544];
  ushort_t (*xtile)[18][XST] = (ushort_t(*)[18][XST])smem;   // 3*18*72*2 = 7776 B
  float (*tapw)[4] = (float(*)[4])smem;                      // 144*16 = 2304 B
  int   (*tapa)[4] = (int(*)[4])(smem + 2304);               // 2304 B
  float (*offm)[16] = (float(*)[16])(smem + 7808);           // 32*16*4 = 2048 B
  ushort_t* cols = (ushort_t*)(smem + 9856);                 // 16*584*2 = 18688 B

  int blk = blockIdx.x;          // 8192 blocks
  int pix0 = blk * 16;
  int b = pix0 / HWHW;
  int hw0 = pix0 % HWHW;
  int y = hw0 / WW;
  int x0 = hw0 % WW;             // 16 consecutive x in one row
  int wave = threadIdx.x >> 6;
  int lane = threadIdx.x & 63;   // = input channel c in staging
  int tid = threadIdx.x;
  const ushort_t* xbu = xtbf + (size_t)b * HWHW * 64;

  // ---- Phase A: stage halo tile ----
#pragma unroll
  for (int ry = 0; ry < 3; ++ry) {
    int yy = y + ry - 1;
    bool yok = ((unsigned)yy < (unsigned)HH);
    for (int xi = wave; xi < 18; xi += 4) {
      int xx = x0 + xi - 1;
      bool ok = yok && ((unsigned)xx < (unsigned)WW);
      ushort_t v = 0;
      if (ok) v = xbu[(size_t)(yy * WW + xx) * 64 + lane];
      xtile[ry][xi][lane] = v;
    }
  }
  __syncthreads();

  // ---- Phase B: offset/mask conv (waves 0,1) ----
  if (wave < 2) {
    int mr = lane & 15;          // A pixel-row AND B o-row
    int kg = lane >> 4;
    f32x4 cacc = {0.f, 0.f, 0.f, 0.f};
    const ushort_t* wrow = w_om + (size_t)(wave * 16 + mr) * 576 + kg * 8;
#pragma unroll
    for (int s = 0; s < 18; ++s) {
      int t = s >> 1;
      int coff = (s & 1) * 32;
      int ky = t / 3, kx = t % 3;              // compile-time
      bf16x8 a = *(const bf16x8*)&xtile[ky][mr + kx][coff + kg * 8];
      bf16x8 bb = *(const bf16x8*)(wrow + s * 32);
      cacc = __builtin_amdgcn_mfma_f32_16x16x32_bf16(a, bb, cacc, 0, 0, 0);
    }
    int o = wave * 16 + mr;
    float bias = 0.f;
    if (o < 18) bias = b_off[o];
    else if (o < 27) bias = b_mask[o - 18];
    bool is_mask = (o >= 18) && (o < 27);
#pragma unroll
    for (int r = 0; r < 4; ++r) {
      float v = cacc[r] + bias;
      if (is_mask) v = 1.f / (1.f + expf(-v));
      cacc[r] = v;
    }
    *(f32x4*)&offm[o][kg * 4] = cacc;   // D rows = pixels kg*4..kg*4+3
  }
  __syncthreads();

  // ---- Phase C1: per-tap setup (threads 0..143) ----
  if (tid < 144) {
    int p = tid / 9;
    int k = tid - p * 9;
    float dy = offm[2 * k][p];
    float dx = offm[2 * k + 1][p];
    float m = offm[18 + k][p];
    int xx = x0 + p;
    float py = (float)(y + k / 3 - 1) + dy;
    float pxf = (float)(xx + k % 3 - 1) + dx;
    float fy = floorf(py), fx = floorf(pxf);
    int y0i = (int)fy, x0i = (int)fx;
    float wy1 = py - fy, wx1 = pxf - fx;
    float wy0 = 1.f - wy1, wx0 = 1.f - wx1;
    float vy0 = ((unsigned)y0i < (unsigned)HH) ? 1.f : 0.f;
    float vy1 = ((unsigned)(y0i + 1) < (unsigned)HH) ? 1.f : 0.f;
    float vx0 = ((unsigned)x0i < (unsigned)WW) ? 1.f : 0.f;
    float vx1 = ((unsigned)(x0i + 1) < (unsigned)WW) ? 1.f : 0.f;
    int y0c = min(max(y0i, 0), HH - 1);
    int y1c = min(max(y0i + 1, 0), HH - 1);
    int x0c = min(max(x0i, 0), WW - 1);
    int x1c = min(max(x0i + 1, 0), WW - 1);
    tapw[tid][0] = wy0 * wx0 * vy0 * vx0 * m;
    tapw[tid][1] = wy0 * wx1 * vy0 * vx1 * m;
    tapw[tid][2] = wy1 * wx0 * vy1 * vx0 * m;
    tapw[tid][3] = wy1 * wx1 * vy1 * vx1 * m;
    tapa[tid][0] = (y0c * WW + x0c) * 64;
    tapa[tid][1] = (y0c * WW + x1c) * 64;
    tapa[tid][2] = (y1c * WW + x0c) * 64;
    tapa[tid][3] = (y1c * WW + x1c) * 64;
  }
  __syncthreads();

  // ---- Phase C2: gather (corner-pair split, batched per 4-px group) ----
  int half = lane >> 5;          // 0: corners 00/01, 1: corners 10/11
  int ch2 = (lane & 31) << 1;    // channel pair base: channels ch2, ch2+1
#pragma unroll
  for (int pp = 0; pp < 4; ++pp) {
    int p = wave * 4 + pp;
    ushort_t* colp = cols + p * CSTR;
    int tb = p * 9;
    float2 wv[9];
    int2 av[9];
#pragma unroll
    for (int k = 0; k < 9; ++k) {          // tap tables: per-half b64 reads
      wv[k] = *(const float2*)&tapw[tb + k][half * 2];
      av[k] = *(const int2*)&tapa[tb + k][half * 2];
    }
    unsigned va[9], vb[9];
#pragma unroll
    for (int k = 0; k < 9; ++k) {          // 18 independent dword loads in flight
      va[k] = *(const unsigned*)(xbu + av[k].x + ch2);
      vb[k] = *(const unsigned*)(xbu + av[k].y + ch2);
    }
#pragma unroll
    for (int k = 0; k < 9; ++k) {
      float a0 = bf2f((ushort_t)(va[k] & 0xffffu));
      float a1 = bf2f((ushort_t)(va[k] >> 16));
      float b0 = bf2f((ushort_t)(vb[k] & 0xffffu));
      float b1 = bf2f((ushort_t)(vb[k] >> 16));
      float f0 = a0 * wv[k].x + b0 * wv[k].y;   // half 0: top row; half 1: bottom
      float f1 = a1 * wv[k].x + b1 * wv[k].y;
      f0 += __shfl_xor(f0, 32, 64);             // combine halves
      f1 += __shfl_xor(f1, 32, 64);
      if (half == 0) {
        unsigned pk = (unsigned)f2bf(f0) | ((unsigned)f2bf(f1) << 16);
        *(unsigned*)(colp + k * 64 + ch2) = pk; // 32 lanes x 4B, conflict-free
      }
    }
  }
  __syncthreads();

  // ---- Phase D: main GEMM (cols[16][576] x wbf[64][576]^T) ----
  int mrow = lane & 15;        // A pixel-row AND B o-row
  int kgrp = lane >> 4;
  int otile = wave * 16;
  f32x4 acc = {0.f, 0.f, 0.f, 0.f};
  const ushort_t* wp = wbf + (size_t)(otile + mrow) * 576 + kgrp * 8;
  const ushort_t* cp = &cols[mrow * CSTR + kgrp * 8];
#pragma unroll
  for (int s = 0; s < 18; ++s) {
    bf16x8 a = *(const bf16x8*)(cp + s * 32);
    bf16x8 bb = *(const bf16x8*)(wp + s * 32);
    acc = __builtin_amdgcn_mfma_f32_16x16x32_bf16(a, bb, acc, 0, 0, 0);
  }
  // D: lane holds out[px=kgrp*4+r][o=otile+mrow], 4 consecutive px -> float4 store
  int o = otile + mrow;
  float* op = out + (size_t)(b * 64 + o) * HWHW + y * WW + x0 + kgrp * 4;
  *(f32x4*)op = acc;
}

extern "C" void kernel_launch(void* const* d_in, const int* in_sizes, int n_in,
                              void* d_out, int out_size, void* d_ws, size_t ws_size,
                              hipStream_t stream) {
  const float* x = (const float*)d_in[0];
  const float* w_off = (const float*)d_in[1];
  const float* b_off = (const float*)d_in[2];
  const float* w_mask = (const float*)d_in[3];
  const float* b_mask = (const float*)d_in[4];
  const float* w_dcn = (const float*)d_in[5];
  float* out = (float*)d_out;

  char* ws = (char*)d_ws;
  ushort_t* xtbf = (ushort_t*)ws;                         // 16,777,216 B
  ushort_t* wbf = (ushort_t*)(ws + 16777216);             //     73,728 B
  ushort_t* w_om = (ushort_t*)(ws + 16777216 + 73728);    //     36,864 B

  hipLaunchKernelGGL(k_transpose, dim3(2048), dim3(256), 0, stream, x, xtbf);
  hipLaunchKernelGGL(k_wcast, dim3(216), dim3(256), 0, stream, w_dcn, w_off, w_mask,
                     wbf, w_om);
  hipLaunchKernelGGL(k_deform, dim3(8192), dim3(256), 0, stream, xtbf, w_om,
                     b_off, b_mask, wbf, out);
}

// Round 7
// 159.388 us; speedup vs baseline: 7.8731x; 1.0789x over previous
//
#include <hip/hip_runtime.h>
#include <hip/hip_bf16.h>
#include <math.h>

#define BB 8
#define CC 64
#define HH 128
#define WW 128
#define OO 64
#define HWHW (HH*WW)

typedef short bf16x8 __attribute__((ext_vector_type(8)));
typedef float f32x4 __attribute__((ext_vector_type(4)));
typedef unsigned short ushort_t;
typedef unsigned int uint32;

__device__ __forceinline__ float bf2f(ushort_t u) {
  unsigned v = ((unsigned)u) << 16;
  return __builtin_bit_cast(float, v);
}
__device__ __forceinline__ ushort_t f2bf(float f) {
  __hip_bfloat16 h = __float2bfloat16(f);
  return *(ushort_t*)&h;
}

// ---------------- Kernel 1: NCHW fp32 -> NHWC bf16 transpose of x ----------------
__global__ __launch_bounds__(256) void k_transpose(const float* __restrict__ x,
                                                   ushort_t* __restrict__ xt) {
  __shared__ float tile[64][65];
  int blk = blockIdx.x;            // 2048 blocks: 8 batches * 256 hw-chunks
  int b = blk >> 8;
  int hw0 = (blk & 255) << 6;      // 64 hw positions per block
  int lane = threadIdx.x & 63;
  int g = threadIdx.x >> 6;        // 0..3
  const float* xb = x + (size_t)b * CC * HWHW;
#pragma unroll
  for (int i = 0; i < 16; ++i) {
    int c = g + i * 4;
    tile[lane][c] = xb[c * HWHW + hw0 + lane];   // coalesced read along hw
  }
  __syncthreads();
  ushort_t* xtb = xt + (size_t)b * HWHW * 64;
#pragma unroll
  for (int j = 0; j < 16; ++j) {
    int hwl = g + j * 4;
    xtb[(size_t)(hw0 + hwl) * 64 + lane] = f2bf(tile[hwl][lane]);  // coalesced along c
  }
}

// ---------------- Kernel 2: weight prep ----------------
// wbf:  w_dcn [O][c*9+t] fp32 -> [O][t*64+c] bf16   (36864 elems)
// w_om: rows 0..17 = w_off, 18..26 = w_mask, 27..31 = 0; [32][t*64+c] bf16 (18432)
__global__ __launch_bounds__(256) void k_wcast(const float* __restrict__ w_dcn,
                                               const float* __restrict__ w_off,
                                               const float* __restrict__ w_mask,
                                               ushort_t* __restrict__ wbf,
                                               ushort_t* __restrict__ w_om) {
  int i = blockIdx.x * 256 + threadIdx.x;   // 216 blocks * 256 = 55296
  if (i < 36864) {
    int o = i / 576;
    int ck = i % 576;
    int c = ck / 9;
    int t = ck % 9;
    wbf[o * 576 + t * 64 + c] = f2bf(w_dcn[i]);
  } else {
    int j = i - 36864;          // 0..18431
    int o = j / 576;
    int r = j % 576;
    int t = r / 64;
    int c = r % 64;
    float v = 0.f;
    if (o < 18) v = w_off[o * 576 + c * 9 + t];
    else if (o < 27) v = w_mask[(o - 18) * 576 + c * 9 + t];
    w_om[j] = f2bf(v);
  }
}

// ---------------- Kernel 3: fused offset-conv + deformable conv ----------------
// Block = 256 thr (4 waves), 16 consecutive-x pixels (one row).
// A: stage xt5 halo [5 rows][20 cols][64 ch] bf16, zero-filled out-of-image,
//    16B-block XOR swizzle per position (bank-spread for phase-B strided reads).
// B: waves 0,1: offset/mask conv via 18 MFMA vs w_om -> offm[32][16] (+sigmoid).
// C1: 144 threads: per (px,tap) 4 corners -> {weight, addr}: addr = LDS pos*128
//     if corner in halo tile else 0x80000000|global-pos (rare fallback, exact).
// C2: lane=(pixel-quarter, channel-quad): per tap 2 broadcast b128 table reads +
//     4 conflict-free b64 corner reads (LDS; global when flagged) + 16 FMA ->
//     bf16 cols. No shfl, no 64-bit addr math in the hot loop.
// D: waves own 16 out-channels; 18 MFMA vs wbf -> out (NCHW float4 stores).
#define CSTR 584      // cols row stride (bf16): 1168 B -> 2-way (free) on D reads
#define SM_TAP  12800 // tap tables: 16 px * 9 taps * 4 corners * {w,v} = 4608 B
#define SM_OFFM 17408 // offm[32][16] f32 = 2048 B
#define SM_COLS 19456 // cols 16*584*2 = 18688 B
#define SM_TOTAL 38144
__global__ __launch_bounds__(256, 4) void k_deform(const ushort_t* __restrict__ xtbf,
                                                   const ushort_t* __restrict__ w_om,
                                                   const float* __restrict__ b_off,
                                                   const float* __restrict__ b_mask,
                                                   const ushort_t* __restrict__ wbf,
                                                   float* __restrict__ out) {
  __shared__ __align__(16) unsigned char smem[SM_TOTAL];
  float (*offm)[16] = (float(*)[16])(smem + SM_OFFM);
  uint32* tap = (uint32*)(smem + SM_TAP);
  ushort_t* cols = (ushort_t*)(smem + SM_COLS);

  int blk = blockIdx.x;          // 8192 blocks
  int pix0 = blk * 16;
  int b = pix0 / HWHW;
  int hw0 = pix0 % HWHW;
  int y = hw0 / WW;
  int x0 = hw0 % WW;             // 16 consecutive x in one row
  int wave = threadIdx.x >> 6;
  int lane = threadIdx.x & 63;
  int tid = threadIdx.x;
  const ushort_t* xbu = xtbf + (size_t)b * HWHW * 64;

  // ---- Phase A: stage 5x20 halo, 4 positions per wave-load ----
  {
    int pq = lane >> 4;           // sub-position 0..3
    int c0 = (lane & 15) * 4;     // first of 4 channels
#pragma unroll
    for (int i = 0; i < 7; ++i) {
      int ii = wave + i * 4;
      if (ii < 25) {
        int pos = ii * 4 + pq;    // 0..99
        int r = pos / 20;
        int j = pos - r * 20;
        int yy = y - 2 + r;
        int xx = x0 - 2 + j;
        bool ok = ((unsigned)yy < (unsigned)HH) && ((unsigned)xx < (unsigned)WW);
        uint2 d = make_uint2(0u, 0u);
        if (ok) d = *(const uint2*)(xbu + (size_t)(yy * WW + xx) * 64 + c0);
        *(uint2*)(smem + pos * 128 + ((c0 * 2) ^ ((pos & 7) << 4))) = d;
      }
    }
  }
  __syncthreads();

  // ---- Phase B: offset/mask conv (waves 0,1) ----
  if (wave < 2) {
    int mr = lane & 15;          // A pixel-row AND B o-row
    int kg = lane >> 4;
    f32x4 cacc = {0.f, 0.f, 0.f, 0.f};
    const ushort_t* wrow = w_om + (size_t)(wave * 16 + mr) * 576 + kg * 8;
#pragma unroll
    for (int s = 0; s < 18; ++s) {
      int t = s >> 1;
      int ky = t / 3, kx = t % 3;              // compile-time
      int pos = (ky + 1) * 20 + (mr + kx + 1);
      int abyte = pos * 128 + ((((s & 1) * 64) + kg * 16) ^ ((pos & 7) << 4));
      bf16x8 a = *(const bf16x8*)(smem + abyte);
      bf16x8 bb = *(const bf16x8*)(wrow + s * 32);
      cacc = __builtin_amdgcn_mfma_f32_16x16x32_bf16(a, bb, cacc, 0, 0, 0);
    }
    int o = wave * 16 + mr;
    float bias = 0.f;
    if (o < 18) bias = b_off[o];
    else if (o < 27) bias = b_mask[o - 18];
    bool is_mask = (o >= 18) && (o < 27);
#pragma unroll
    for (int r = 0; r < 4; ++r) {
      float v = cacc[r] + bias;
      if (is_mask) v = 1.f / (1.f + expf(-v));
      cacc[r] = v;
    }
    *(f32x4*)&offm[o][kg * 4] = cacc;
  }
  __syncthreads();

  // ---- Phase C1: per-tap corner tables (threads 0..143) ----
  if (tid < 144) {
    int p = tid / 9;
    int k = tid - p * 9;
    float dy = offm[2 * k][p];
    float dx = offm[2 * k + 1][p];
    float m = offm[18 + k][p];
    int xx = x0 + p;
    float py = (float)(y + k / 3 - 1) + dy;
    float pxf = (float)(xx + k % 3 - 1) + dx;
    float fy = floorf(py), fx = floorf(pxf);
    int y0i = (int)fy, x0i = (int)fx;
    float wy1 = py - fy, wx1 = pxf - fx;
    float wyv[2] = {1.f - wy1, wy1};
    float wxv[2] = {1.f - wx1, wx1};
    uint32 ev[8];
#pragma unroll
    for (int ry = 0; ry < 2; ++ry) {
#pragma unroll
      for (int rx = 0; rx < 2; ++rx) {
        int yiq = y0i + ry;
        int xiq = x0i + rx;
        float valid = (((unsigned)yiq < (unsigned)HH) && ((unsigned)xiq < (unsigned)WW))
                          ? 1.f : 0.f;
        int yc = min(max(yiq, 0), HH - 1);
        int xc = min(max(xiq, 0), WW - 1);
        int rr = yc - (y - 2);
        int jj = xc - (x0 - 2);
        uint32 v;
        if ((unsigned)rr < 5u && (unsigned)jj < 20u)
          v = (uint32)((rr * 20 + jj) * 128);          // LDS byte base of position
        else
          v = 0x80000000u | (uint32)(yc * WW + xc);    // rare: global position
        float w = wyv[ry] * wxv[rx] * valid * m;
        int e = (ry * 2 + rx) * 2;
        ev[e] = __builtin_bit_cast(uint32, w);
        ev[e + 1] = v;
      }
    }
    uint32* tp = tap + p * 72 + k * 8;
    *(uint4*)(tp) = make_uint4(ev[0], ev[1], ev[2], ev[3]);
    *(uint4*)(tp + 4) = make_uint4(ev[4], ev[5], ev[6], ev[7]);
  }
  __syncthreads();

  // ---- Phase C2: gather from LDS halo (lane = pixel-quarter x channel-quad) ----
  {
    int p = wave * 4 + (lane >> 4);
    int l4 = lane & 15;
    int chb = l4 * 8;      // byte offset of 4 channels within a position
    int ch4 = l4 * 4;      // element offset (global fallback)
    const uint32* tp = tap + p * 72;
    ushort_t* colp = cols + p * CSTR;
#pragma unroll
    for (int k = 0; k < 9; ++k) {
      uint4 e01 = *(const uint4*)(tp + k * 8);
      uint4 e23 = *(const uint4*)(tp + k * 8 + 4);
      uint32 wv[4] = {e01.x, e01.z, e23.x, e23.z};
      uint32 vv[4] = {e01.y, e01.w, e23.y, e23.w};
      float a0 = 0.f, a1 = 0.f, a2 = 0.f, a3 = 0.f;
#pragma unroll
      for (int c = 0; c < 4; ++c) {
        float w = __builtin_bit_cast(float, wv[c]);
        uint32 v = vv[c];
        uint2 d;
        if ((int)v >= 0) {
          d = *(const uint2*)(smem + v + (chb ^ ((v >> 3) & 0x70)));
        } else {
          d = *(const uint2*)(xbu + (size_t)(v & 0x7fffffffu) * 64 + ch4);
        }
        a0 += w * bf2f((ushort_t)(d.x & 0xffffu));
        a1 += w * bf2f((ushort_t)(d.x >> 16));
        a2 += w * bf2f((ushort_t)(d.y & 0xffffu));
        a3 += w * bf2f((ushort_t)(d.y >> 16));
      }
      uint32 lo = (uint32)f2bf(a0) | ((uint32)f2bf(a1) << 16);
      uint32 hi = (uint32)f2bf(a2) | ((uint32)f2bf(a3) << 16);
      *(uint2*)(colp + k * 64 + ch4) = make_uint2(lo, hi);
    }
  }
  __syncthreads();

  // ---- Phase D: main GEMM (cols[16][576] x wbf[64][576]^T) ----
  int mrow = lane & 15;        // A pixel-row AND B o-row
  int kgrp = lane >> 4;
  int otile = wave * 16;
  f32x4 acc = {0.f, 0.f, 0.f, 0.f};
  const ushort_t* wp = wbf + (size_t)(otile + mrow) * 576 + kgrp * 8;
  const ushort_t* cp = cols + mrow * CSTR + kgrp * 8;
#pragma unroll
  for (int s = 0; s < 18; ++s) {
    bf16x8 a = *(const bf16x8*)(cp + s * 32);
    bf16x8 bb = *(const bf16x8*)(wp + s * 32);
    acc = __builtin_amdgcn_mfma_f32_16x16x32_bf16(a, bb, acc, 0, 0, 0);
  }
  // D: lane holds out[px=kgrp*4+r][o=otile+mrow], 4 consecutive px -> float4 store
  int o = otile + mrow;
  float* op = out + (size_t)(b * 64 + o) * HWHW + y * WW + x0 + kgrp * 4;
  *(f32x4*)op = acc;
}

extern "C" void kernel_launch(void* const* d_in, const int* in_sizes, int n_in,
                              void* d_out, int out_size, void* d_ws, size_t ws_size,
                              hipStream_t stream) {
  const float* x = (const float*)d_in[0];
  const float* w_off = (const float*)d_in[1];
  const float* b_off = (const float*)d_in[2];
  const float* w_mask = (const float*)d_in[3];
  const float* b_mask = (const float*)d_in[4];
  const float* w_dcn = (const float*)d_in[5];
  float* out = (float*)d_out;

  char* ws = (char*)d_ws;
  ushort_t* xtbf = (ushort_t*)ws;                         // 16,777,216 B
  ushort_t* wbf = (ushort_t*)(ws + 16777216);             //     73,728 B
  ushort_t* w_om = (ushort_t*)(ws + 16777216 + 73728);    //     36,864 B

  hipLaunchKernelGGL(k_transpose, dim3(2048), dim3(256), 0, stream, x, xtbf);
  hipLaunchKernelGGL(k_wcast, dim3(216), dim3(256), 0, stream, w_dcn, w_off, w_mask,
                     wbf, w_om);
  hipLaunchKernelGGL(k_deform, dim3(8192), dim3(256), 0, stream, xtbf, w_om,
                     b_off, b_mask, wbf, out);
}

// Round 8
// 138.984 us; speedup vs baseline: 9.0289x; 1.1468x over previous
//
#include <hip/hip_runtime.h>
#include <hip/hip_bf16.h>
#include <math.h>

#define BB 8
#define CC 64
#define HH 128
#define WW 128
#define OO 64
#define HWHW (HH*WW)

typedef short bf16x8 __attribute__((ext_vector_type(8)));
typedef float f32x4 __attribute__((ext_vector_type(4)));
typedef unsigned short ushort_t;
typedef unsigned int uint32;

__device__ __forceinline__ float bf2f(ushort_t u) {
  unsigned v = ((unsigned)u) << 16;
  return __builtin_bit_cast(float, v);
}
__device__ __forceinline__ ushort_t f2bf(float f) {
  __hip_bfloat16 h = __float2bfloat16(f);
  return *(ushort_t*)&h;
}
__device__ __forceinline__ float bflo(uint32 u) {
  return __builtin_bit_cast(float, u << 16);
}
__device__ __forceinline__ float bfhi(uint32 u) {
  return __builtin_bit_cast(float, u & 0xffff0000u);
}

// ---------------- Kernel 1: NCHW fp32 -> NHWC bf16 transpose of x ----------------
__global__ __launch_bounds__(256) void k_transpose(const float* __restrict__ x,
                                                   ushort_t* __restrict__ xt) {
  __shared__ float tile[64][65];
  int blk = blockIdx.x;            // 2048 blocks: 8 batches * 256 hw-chunks
  int b = blk >> 8;
  int hw0 = (blk & 255) << 6;      // 64 hw positions per block
  int lane = threadIdx.x & 63;
  int g = threadIdx.x >> 6;        // 0..3
  const float* xb = x + (size_t)b * CC * HWHW;
#pragma unroll
  for (int i = 0; i < 16; ++i) {
    int c = g + i * 4;
    tile[lane][c] = xb[c * HWHW + hw0 + lane];   // coalesced read along hw
  }
  __syncthreads();
  ushort_t* xtb = xt + (size_t)b * HWHW * 64;
#pragma unroll
  for (int j = 0; j < 16; ++j) {
    int hwl = g + j * 4;
    xtb[(size_t)(hw0 + hwl) * 64 + lane] = f2bf(tile[hwl][lane]);  // coalesced along c
  }
}

// ---------------- Kernel 2: weight prep ----------------
// wbf:  w_dcn [O][c*9+t] fp32 -> [O][t*64+c] bf16   (36864 elems)
// w_om: rows 0..17 = w_off, 18..26 = w_mask, 27..31 = 0; [32][t*64+c] bf16 (18432)
__global__ __launch_bounds__(256) void k_wcast(const float* __restrict__ w_dcn,
                                               const float* __restrict__ w_off,
                                               const float* __restrict__ w_mask,
                                               ushort_t* __restrict__ wbf,
                                               ushort_t* __restrict__ w_om) {
  int i = blockIdx.x * 256 + threadIdx.x;   // 216 blocks * 256 = 55296
  if (i < 36864) {
    int o = i / 576;
    int ck = i % 576;
    int c = ck / 9;
    int t = ck % 9;
    wbf[o * 576 + t * 64 + c] = f2bf(w_dcn[i]);
  } else {
    int j = i - 36864;          // 0..18431
    int o = j / 576;
    int r = j % 576;
    int t = r / 64;
    int c = r % 64;
    float v = 0.f;
    if (o < 18) v = w_off[o * 576 + c * 9 + t];
    else if (o < 27) v = w_mask[(o - 18) * 576 + c * 9 + t];
    w_om[j] = f2bf(v);
  }
}

// ---------------- Kernel 3: fused offset-conv + deformable conv (K-split) ----------------
// Block = 256 thr (4 waves), 16 consecutive-x pixels (one row).
// A: stage halo [100 pos = 5r x 20c][144B-stride] bf16, zero-filled OOB.
// B: waves 0,1: offset/mask conv, 18 MFMA vs w_om -> offm[32][16] (+sigmoid).
// C1: 144 threads: per (px,tap): 4 corner {f32 weight(premult mask+valid),
//     addr = halo byte base | 0x80000000|global-pos fallback} -> tapW/tapA[9][16].
// G: K-SPLIT gather+GEMM: wave w does K-steps {w, w+4, ...} of 18 (tap x half).
//    lane=(mr=pixel,kg=k-quad) builds its OWN A-frag: 4 corner b128 halo reads
//    + 32 FMA + round-half-up v_perm pack -> 4 MFMA (one per 16-o tile).
//    No cols buffer, no separate D pass.
// R: 2-level LDS tree reduction of the 4 waves' C partials (8KB overlaid on
//    dead halo); wave 0 stores NCHW float4.
// __launch_bounds__(256,5): VGPR cap 102 (sized ~90 live; r2/r3/r5: caps of
// 32/64 spilled, unbounded squeezed to 48 and serialized).
#define HALO_OFF 0        // 100 * 144 = 14400 B
#define TAPW_OFF 14400    // [9][16] uint4 = 2304 B
#define TAPA_OFF 16704    // [9][16] uint4 = 2304 B
#define OFFM_OFF 19008    // [32][16] f32 = 2048 B
#define RED_OFF  0        // overlay on halo (dead after G): [2][4][64] f32x4 = 8192 B
#define SM_TOTAL 21056
__global__ __launch_bounds__(256, 5) void k_deform(const ushort_t* __restrict__ xtbf,
                                                   const ushort_t* __restrict__ w_om,
                                                   const float* __restrict__ b_off,
                                                   const float* __restrict__ b_mask,
                                                   const ushort_t* __restrict__ wbf,
                                                   float* __restrict__ out) {
  __shared__ __align__(16) unsigned char smem[SM_TOTAL];
  float (*offm)[16] = (float(*)[16])(smem + OFFM_OFF);

  int blk = blockIdx.x;          // 8192 blocks
  int pix0 = blk * 16;
  int b = pix0 / HWHW;
  int hw0 = pix0 % HWHW;
  int y = hw0 / WW;
  int x0 = hw0 % WW;             // 16 consecutive x in one row
  int tid = threadIdx.x;
  int wave = tid >> 6;
  int lane = tid & 63;
  int mr = lane & 15;            // pixel row (A row) and o-row (B)
  int kg = lane >> 4;            // k-quad 0..3
  const ushort_t* xbu = xtbf + (size_t)b * HWHW * 64;

  // ---- Phase A: stage 5x20 halo (16 thr/pos, 8B each = 128B of 144B slot) ----
  {
    int c8 = (tid & 15) * 8;     // byte offset of 4 channels
#pragma unroll
    for (int i = 0; i < 7; ++i) {
      int pos = (tid >> 4) + i * 16;
      if (pos < 100) {
        int r = pos / 20;
        int j = pos - r * 20;
        int yy = y - 2 + r;
        int xx = x0 - 2 + j;
        uint2 d = make_uint2(0u, 0u);
        if (((unsigned)yy < (unsigned)HH) && ((unsigned)xx < (unsigned)WW))
          d = *(const uint2*)((const char*)xbu + (size_t)(yy * WW + xx) * 128 + c8);
        *(uint2*)(smem + pos * 144 + c8) = d;
      }
    }
  }
  __syncthreads();

  // ---- Phase B: offset/mask conv (waves 0,1) ----
  if (wave < 2) {
    f32x4 cacc = {0.f, 0.f, 0.f, 0.f};
    const ushort_t* wrow = w_om + (size_t)(wave * 16 + mr) * 576 + kg * 8;
#pragma unroll
    for (int s = 0; s < 18; ++s) {
      int t = s >> 1;
      int ky = t / 3, kx = t % 3;              // compile-time
      int pos = (ky + 1) * 20 + (mr + kx + 1);
      bf16x8 a = *(const bf16x8*)(smem + pos * 144 + (s & 1) * 64 + kg * 16);
      bf16x8 bb = *(const bf16x8*)(wrow + s * 32);
      cacc = __builtin_amdgcn_mfma_f32_16x16x32_bf16(a, bb, cacc, 0, 0, 0);
    }
    int o = wave * 16 + mr;
    float bias = 0.f;
    if (o < 18) bias = b_off[o];
    else if (o < 27) bias = b_mask[o - 18];
    bool is_mask = (o >= 18) && (o < 27);
#pragma unroll
    for (int r = 0; r < 4; ++r) {
      float v = cacc[r] + bias;
      if (is_mask) v = 1.f / (1.f + expf(-v));
      cacc[r] = v;
    }
    *(f32x4*)&offm[o][kg * 4] = cacc;
  }
  __syncthreads();

  // ---- Phase C1: per-tap corner tables (threads 0..143) ----
  if (tid < 144) {
    int p = tid / 9;
    int k = tid - p * 9;
    float dy = offm[2 * k][p];
    float dx = offm[2 * k + 1][p];
    float m = offm[18 + k][p];
    int xx = x0 + p;
    float py = (float)(y + k / 3 - 1) + dy;
    float pxf = (float)(xx + k % 3 - 1) + dx;
    float fy = floorf(py), fx = floorf(pxf);
    int y0i = (int)fy, x0i = (int)fx;
    float wy1 = py - fy, wx1 = pxf - fx;
    float wyv[2] = {1.f - wy1, wy1};
    float wxv[2] = {1.f - wx1, wx1};
    uint32 wq[4], aq[4];
#pragma unroll
    for (int ry = 0; ry < 2; ++ry) {
#pragma unroll
      for (int rx = 0; rx < 2; ++rx) {
        int yiq = y0i + ry;
        int xiq = x0i + rx;
        float valid = (((unsigned)yiq < (unsigned)HH) && ((unsigned)xiq < (unsigned)WW))
                          ? 1.f : 0.f;
        int yc = min(max(yiq, 0), HH - 1);
        int xc = min(max(xiq, 0), WW - 1);
        int rr = yc - (y - 2);
        int jj = xc - (x0 - 2);
        uint32 v;
        if ((unsigned)rr < 5u && (unsigned)jj < 20u)
          v = (uint32)((rr * 20 + jj) * 144);          // LDS byte base of position
        else
          v = 0x80000000u | (uint32)(yc * WW + xc);    // rare: global position
        int e = ry * 2 + rx;
        wq[e] = __builtin_bit_cast(uint32, wyv[ry] * wxv[rx] * valid * m);
        aq[e] = v;
      }
    }
    *(uint4*)(smem + TAPW_OFF + (k * 16 + p) * 16) = make_uint4(wq[0], wq[1], wq[2], wq[3]);
    *(uint4*)(smem + TAPA_OFF + (k * 16 + p) * 16) = make_uint4(aq[0], aq[1], aq[2], aq[3]);
  }
  __syncthreads();

  // ---- Phase G: K-split gather + MFMA ----
  f32x4 acc[4] = {{0.f, 0.f, 0.f, 0.f}, {0.f, 0.f, 0.f, 0.f},
                  {0.f, 0.f, 0.f, 0.f}, {0.f, 0.f, 0.f, 0.f}};
#pragma unroll
  for (int i = 0; i < 5; ++i) {
    int u = wave + i * 4;                    // K-step 0..17 (tap t, half h)
    if (u < 18) {
      int t = u >> 1;
      int h = u & 1;
      uint4 wq = *(const uint4*)(smem + TAPW_OFF + (t * 16 + mr) * 16);
      uint4 aq = *(const uint4*)(smem + TAPA_OFF + (t * 16 + mr) * 16);
      int cb = h * 64 + kg * 16;             // byte offset of this lane's 8 channels
      float s0 = 0.f, s1 = 0.f, s2 = 0.f, s3 = 0.f,
            s4 = 0.f, s5 = 0.f, s6 = 0.f, s7 = 0.f;
#define CORNER(WV, AV)                                                          \
      {                                                                         \
        uint4 d;                                                               \
        if ((int)(AV) >= 0)                                                     \
          d = *(const uint4*)(smem + (AV) + cb);                                \
        else                                                                    \
          d = *(const uint4*)((const char*)xbu +                                \
                              (size_t)((AV) & 0x7fffffffu) * 128 + cb);         \
        float fw = __builtin_bit_cast(float, (WV));                             \
        s0 += fw * bflo(d.x); s1 += fw * bfhi(d.x);                             \
        s2 += fw * bflo(d.y); s3 += fw * bfhi(d.y);                             \
        s4 += fw * bflo(d.z); s5 += fw * bfhi(d.z);                             \
        s6 += fw * bflo(d.w); s7 += fw * bfhi(d.w);                             \
      }
      CORNER(wq.x, aq.x)
      CORNER(wq.y, aq.y)
      CORNER(wq.z, aq.z)
      CORNER(wq.w, aq.w)
#undef CORNER
      // pack 8 f32 -> bf16x8, round-half-up (bits+0x8000) + v_perm hi16 pairs
      uint32 p0 = __builtin_amdgcn_perm(__builtin_bit_cast(uint32, s1) + 0x8000u,
                                        __builtin_bit_cast(uint32, s0) + 0x8000u,
                                        0x07060302u);
      uint32 p1 = __builtin_amdgcn_perm(__builtin_bit_cast(uint32, s3) + 0x8000u,
                                        __builtin_bit_cast(uint32, s2) + 0x8000u,
                                        0x07060302u);
      uint32 p2 = __builtin_amdgcn_perm(__builtin_bit_cast(uint32, s5) + 0x8000u,
                                        __builtin_bit_cast(uint32, s4) + 0x8000u,
                                        0x07060302u);
      uint32 p3 = __builtin_amdgcn_perm(__builtin_bit_cast(uint32, s7) + 0x8000u,
                                        __builtin_bit_cast(uint32, s6) + 0x8000u,
                                        0x07060302u);
      bf16x8 afrag = __builtin_bit_cast(bf16x8, make_uint4(p0, p1, p2, p3));
      const ushort_t* wp = wbf + (size_t)mr * 576 + t * 64 + h * 32 + kg * 8;
#pragma unroll
      for (int n = 0; n < 4; ++n) {
        bf16x8 bfr = *(const bf16x8*)(wp + (size_t)n * 16 * 576);
        acc[n] = __builtin_amdgcn_mfma_f32_16x16x32_bf16(afrag, bfr, acc[n], 0, 0, 0);
      }
    }
  }

  // ---- Phase R: tree-reduce 4 waves' partials; wave 0 stores ----
  __syncthreads();                       // halo dead beyond this point
  f32x4* red = (f32x4*)(smem + RED_OFF); // [2][4][64]
  if (wave >= 2) {
#pragma unroll
    for (int n = 0; n < 4; ++n) red[(wave - 2) * 256 + n * 64 + lane] = acc[n];
  }
  __syncthreads();
  if (wave < 2) {
#pragma unroll
    for (int n = 0; n < 4; ++n) acc[n] += red[wave * 256 + n * 64 + lane];
  }
  __syncthreads();
  if (wave == 1) {
#pragma unroll
    for (int n = 0; n < 4; ++n) red[n * 64 + lane] = acc[n];
  }
  __syncthreads();
  if (wave == 0) {
#pragma unroll
    for (int n = 0; n < 4; ++n) {
      f32x4 v = acc[n] + red[n * 64 + lane];
      // C/D layout: lane holds D[px=kg*4+r][o=n*16+mr]
      float* op = out + (size_t)(b * 64 + n * 16 + mr) * HWHW + y * WW + x0 + kg * 4;
      *(f32x4*)op = v;
    }
  }
}

extern "C" void kernel_launch(void* const* d_in, const int* in_sizes, int n_in,
                              void* d_out, int out_size, void* d_ws, size_t ws_size,
                              hipStream_t stream) {
  const float* x = (const float*)d_in[0];
  const float* w_off = (const float*)d_in[1];
  const float* b_off = (const float*)d_in[2];
  const float* w_mask = (const float*)d_in[3];
  const float* b_mask = (const float*)d_in[4];
  const float* w_dcn = (const float*)d_in[5];
  float* out = (float*)d_out;

  char* ws = (char*)d_ws;
  ushort_t* xtbf = (ushort_t*)ws;                         // 16,777,216 B
  ushort_t* wbf = (ushort_t*)(ws + 16777216);             //     73,728 B
  ushort_t* w_om = (ushort_t*)(ws + 16777216 + 73728);    //     36,864 B

  hipLaunchKernelGGL(k_transpose, dim3(2048), dim3(256), 0, stream, x, xtbf);
  hipLaunchKernelGGL(k_wcast, dim3(216), dim3(256), 0, stream, w_dcn, w_off, w_mask,
                     wbf, w_om);
  hipLaunchKernelGGL(k_deform, dim3(8192), dim3(256), 0, stream, xtbf, w_om,
                     b_off, b_mask, wbf, out);
}